// Round 10
// baseline (208.703 us; speedup 1.0000x reference)
//
#include <hip/hip_runtime.h>

#define T_SEQ 2048
#define DM 1024
#define NH 16
#define HD 64
// SCALE * log2(e) : softmax computed in exp2 domain (folded into Q in qkv_gemm)
#define SC2 0.1803368801111731f
#define LS 72   // ps LDS row stride (u16); 144 B rows: 16B-aligned, 2-way banks (free)

typedef unsigned short u16;
typedef unsigned int u32;
typedef __attribute__((ext_vector_type(8))) short bf16x8;
typedef __attribute__((ext_vector_type(4))) float f32x4;

static __device__ __forceinline__ f32x4 mfma16(bf16x8 a, bf16x8 b, f32x4 c) {
    return __builtin_amdgcn_mfma_f32_16x16x32_bf16(a, b, c, 0, 0, 0);
}
static __device__ __forceinline__ float bf2f(u16 u) {
    union { u32 i; float f; } v; v.i = ((u32)u) << 16; return v.f;
}
static __device__ __forceinline__ u16 f2bf(float f) {
    union { float f; u32 i; } v; v.f = f;
    u32 x = v.i;
    x += 0x7FFFu + ((x >> 16) & 1u);   // RNE
    return (u16)(x >> 16);
}
static __device__ __forceinline__ u16 f2bf_t(float f) {   // truncating (1 op)
    union { float f; u32 i; } v; v.f = f;
    return (u16)(v.i >> 16);
}
static __device__ __forceinline__ u32 pk2(float lo, float hi) {
    return (u32)f2bf(lo) | ((u32)f2bf(hi) << 16);
}
// load 8 contiguous elements as packed bf16; converts from f32 if f==0.
static __device__ __forceinline__ uint4 ld8(const void* src, size_t idx, int f) {
    if (f) return *(const uint4*)((const u16*)src + idx);
    const float* s = (const float*)src + idx;
    uint4 a = *(const uint4*)s;
    uint4 b = *(const uint4*)(s + 4);
    const float* af = (const float*)&a;
    const float* bf = (const float*)&b;
    uint4 r;
    r.x = pk2(af[0], af[1]); r.y = pk2(af[2], af[3]);
    r.z = pk2(bf[0], bf[1]); r.w = pk2(bf[2], bf[3]);
    return r;
}
static __device__ __forceinline__ float qsum16(float v) {
#pragma unroll
    for (int o = 1; o < 16; o <<= 1) v += __shfl_xor(v, o, 64);
    return v;
}
static __device__ __forceinline__ float ex2(float x) {
    return __builtin_amdgcn_exp2f(x);
}

// Async global->LDS DMA, 16 B per lane.
static __device__ __forceinline__ void gl16(const u16* g, u16* l) {
    __builtin_amdgcn_global_load_lds(
        (const __attribute__((address_space(1))) void*)g,
        (__attribute__((address_space(3))) void*)l,
        16, 0, 0);
}

// ---------------------------------------------------------------------------
// Staging into unpadded LDS (row stride 64 u16 = 128 B) with XOR chunk
// swizzle: LDS slot (r, c) holds global chunk c^(r&7). Global side fully
// coalesced; b128 fragment reads land 2-way (free). r7 lesson: direct
// global fragment loads (no LDS) are 16x transaction-amplified -- keep LDS.
// ---------------------------------------------------------------------------
template <int NISS>
static __device__ __forceinline__ void stage_async(const u16* src, size_t row0,
                                                   size_t lds_, size_t col0,
                                                   u16* dst, int tid) {
#pragma unroll
    for (int it = 0; it < NISS; it++) {
        int r = it * 32 + (tid >> 3);
        int cg = (tid & 7) ^ (r & 7);
        gl16(&src[(row0 + r) * lds_ + col0 + cg * 8], &dst[(it * 256 + tid) * 8]);
    }
}
template <int NISS>
static __device__ __forceinline__ void stage_sync(const void* src, size_t row0,
                                                  size_t lds_, size_t col0,
                                                  u16* dst, int tid, int f) {
#pragma unroll
    for (int it = 0; it < NISS; it++) {
        int r = it * 32 + (tid >> 3);
        int cg = (tid & 7) ^ (r & 7);
        *(uint4*)(&dst[(it * 256 + tid) * 8]) =
            ld8(src, (row0 + r) * lds_ + col0 + cg * 8, f);
    }
}
static __device__ __forceinline__ bf16x8 frag(const u16* buf, int R, int co) {
    return *(const bf16x8*)(&buf[R * 64 + co]);
}

// dtype self-detect helper: count plausible bf16 exponents in first 1024
// even-index u16s of x. bf16 N(0,1) -> ~100% hit; f32 mantissa halves ~12%.
static __device__ __forceinline__ int detect_flag(const u16* x, int tid,
                                                  int* tot /*LDS*/) {
    if (tid == 0) *tot = 0;
    __syncthreads();
    int c = 0;
#pragma unroll
    for (int i = 0; i < 4; i++) {
        u16 v = x[2 * (tid * 4 + i)];
        int e = (v >> 7) & 0xFF;
        c += (e >= 110 && e <= 140) ? 1 : 0;
    }
    atomicAdd(tot, c);
    __syncthreads();
    return (*tot >= 512) ? 1 : 0;
}

// ---------------------------------------------------------------------------
// QKV(+V-transpose) projection GEMM. Tile 128x128xK64, async DMA dbuf
// (64 KB LDS -> 2 blocks/CU; grid 512). Self-detects dtype flag (publishes
// to ws for downstream kernels). Q output pre-scaled by SC2.
// Parked at the m97-structure plateau (~240 TF at this shape, m102 curve).
// ---------------------------------------------------------------------------
__global__ __launch_bounds__(256) void qkv_gemm(
    const void* __restrict__ xs, const void* __restrict__ wq,
    const void* __restrict__ wk1, const void* __restrict__ wk2,
    const void* __restrict__ wv, int* __restrict__ flag,
    u16* __restrict__ qd, u16* __restrict__ k1d, u16* __restrict__ k2d,
    u16* __restrict__ vtd) {
    __shared__ __align__(16) u16 As[2][128 * 64];
    __shared__ __align__(16) u16 Bs[2][128 * 64];
    __shared__ int flg_tot;

    const int tid = threadIdx.x;
    const int f = detect_flag((const u16*)xs, tid, &flg_tot);
    if (blockIdx.x == 0 && blockIdx.y == 0 && tid == 0) *flag = f;

    const int w = blockIdx.x >> 3;
    const int n0 = (blockIdx.x & 7) * 128;
    const int m0 = blockIdx.y * 128;
    const void* Bpv = (w == 0) ? wq : (w == 1) ? wk1 : (w == 2) ? wk2 : wv;
    const u16* xb = (const u16*)xs;
    const u16* Bb = (const u16*)Bpv;

    const int lane = tid & 63, wave = tid >> 6;
    const int lr = lane & 15, quad = lane >> 4;
    const int wm = (wave >> 1) * 64, wn = (wave & 1) * 64;
    const int sw = lr & 7;

    f32x4 acc[4][4];
#pragma unroll
    for (int i = 0; i < 4; i++)
#pragma unroll
        for (int j = 0; j < 4; j++) acc[i][j] = (f32x4){0.f, 0.f, 0.f, 0.f};

    if (f) {
        stage_async<4>(xb, m0, DM, 0, As[0], tid);
        stage_async<4>(Bb, n0, DM, 0, Bs[0], tid);
    }
    for (int k0 = 0; k0 < DM; k0 += 64) {
        const int cur = (k0 >> 6) & 1;
        __syncthreads();
        if (f) {
            if (k0 + 64 < DM) {
                stage_async<4>(xb, m0, DM, k0 + 64, As[cur ^ 1], tid);
                stage_async<4>(Bb, n0, DM, k0 + 64, Bs[cur ^ 1], tid);
            }
        } else {
            stage_sync<4>(xs, m0, DM, k0, As[cur], tid, 0);
            stage_sync<4>(Bpv, n0, DM, k0, Bs[cur], tid, 0);
            __syncthreads();
        }
#pragma unroll
        for (int kk = 0; kk < 2; kk++) {
            const int co = ((kk * 4 + quad) ^ sw) * 8;
            bf16x8 af[4], bfr[4];
#pragma unroll
            for (int i = 0; i < 4; i++) af[i] = frag(As[cur], wm + i * 16 + lr, co);
#pragma unroll
            for (int j = 0; j < 4; j++) bfr[j] = frag(Bs[cur], wn + j * 16 + lr, co);
#pragma unroll
            for (int i = 0; i < 4; i++)
#pragma unroll
                for (int j = 0; j < 4; j++) acc[i][j] = mfma16(af[i], bfr[j], acc[i][j]);
        }
    }

#pragma unroll
    for (int i = 0; i < 4; i++)
#pragma unroll
        for (int j = 0; j < 4; j++)
#pragma unroll
            for (int r = 0; r < 4; r++) {
                int t = m0 + wm + i * 16 + quad * 4 + r;
                int o = n0 + wn + j * 16 + lr;
                float val = acc[i][j][r];
                if (w == 0) val *= SC2;               // fold softmax scale into Q
                u16 vbits = f2bf(val);
                int hh = o >> 6, d0 = o & 63;
                if (w == 3)
                    vtd[((size_t)hh * HD + d0) * T_SEQ + t] = vbits;   // v transposed
                else
                    ((w == 0) ? qd : (w == 1) ? k1d : k2d)[((size_t)hh * T_SEQ + t) * HD + d0] = vbits;
            }
}

// ---------------------------------------------------------------------------
// Mapping for attn_a/attn_b: b -> (par, h, qt). par = b>>9 (attn_a grid 2048
// -> par 0..3; attn_b grid 1024 -> par 0..1). Within a 512-group, CU-paired
// qt balance: {qt, 31-qt}. Block processes strip kt ≡ par (mod npar).
// ---------------------------------------------------------------------------
#define ATTN_MAP()                                            \
    const int b = blockIdx.x;                                 \
    const int par = b >> 9;                                   \
    const int rem = b & 511;                                  \
    const int h = rem & 15;                                   \
    const int bi = rem >> 4;                                  \
    const int qt = (bi < 16) ? bi : 47 - bi;                  \
    const int t0 = qt * 64;                                   \
    const int tid = threadIdx.x;                              \
    const int lane = tid & 63, wave = tid >> 6;               \
    const int lr = lane & 15, quad = lane >> 4;               \
    const int wm = wave * 16;                                 \
    const int sw = lr & 7;

// ---------------------------------------------------------------------------
// attn_a: partial Z1/Z2 over the kt ≡ par (mod 4) strip. Grid 2048 ->
// 8 blocks/CU (16 KB LDS). zp: [par*2+which][NH][T] f32.
// ---------------------------------------------------------------------------
__global__ __launch_bounds__(256) void attn_a(
    const u16* __restrict__ qg, const u16* __restrict__ k1g,
    const u16* __restrict__ k2g, float* __restrict__ zp) {
    __shared__ __align__(16) u16 k1s[64 * 64];
    __shared__ __align__(16) u16 k2s[64 * 64];
    ATTN_MAP();

    const u16* qh = qg + (size_t)h * T_SEQ * HD;
    const u16* k1h = k1g + (size_t)h * T_SEQ * HD;
    const u16* k2h = k2g + (size_t)h * T_SEQ * HD;

    bf16x8 aq[2];
#pragma unroll
    for (int kk = 0; kk < 2; kk++)
        aq[kk] = *(const bf16x8*)(&qh[(size_t)(t0 + wm + lr) * HD + kk * 32 + quad * 8]);

    float z1a[4] = {0.f, 0.f, 0.f, 0.f}, z2a[4] = {0.f, 0.f, 0.f, 0.f};

    for (int kt = par; kt <= qt; kt += 4) {
        __syncthreads();   // protect LDS from previous iteration's readers
        stage_async<2>(k1h, (size_t)kt * 64, HD, 0, k1s, tid);
        stage_async<2>(k2h, (size_t)kt * 64, HD, 0, k2s, tid);
        __syncthreads();   // drains vmcnt -> data visible

        f32x4 sa[4], sb[4];
#pragma unroll
        for (int j = 0; j < 4; j++) { sa[j] = (f32x4){0.f,0.f,0.f,0.f}; sb[j] = (f32x4){0.f,0.f,0.f,0.f}; }
#pragma unroll
        for (int kk = 0; kk < 2; kk++) {
            const int co = ((kk * 4 + quad) ^ sw) * 8;
#pragma unroll
            for (int j = 0; j < 4; j++) {
                sa[j] = mfma16(aq[kk], frag(k1s, j * 16 + lr, co), sa[j]);
                sb[j] = mfma16(aq[kk], frag(k2s, j * 16 + lr, co), sb[j]);
            }
        }

        if (kt < qt) {
#pragma unroll
            for (int r = 0; r < 4; r++)
#pragma unroll
                for (int j = 0; j < 4; j++) {
                    z1a[r] += ex2(sa[j][r]);
                    z2a[r] += ex2(sb[j][r]);
                }
        } else {
#pragma unroll
            for (int r = 0; r < 4; r++) {
                const int grow = t0 + wm + quad * 4 + r;
#pragma unroll
                for (int j = 0; j < 4; j++) {
                    int gcol = kt * 64 + j * 16 + lr;
                    if (gcol <= grow) {
                        z1a[r] += ex2(sa[j][r]);
                        z2a[r] += ex2(sb[j][r]);
                    }
                }
            }
        }
    }

#pragma unroll
    for (int r = 0; r < 4; r++) {
        float s1 = qsum16(z1a[r]);
        float s2 = qsum16(z2a[r]);
        if (lr == 0) {
            int row = t0 + wm + quad * 4 + r;
            zp[((size_t)(par * 2 + 0) * NH + h) * T_SEQ + row] = s1;
            zp[((size_t)(par * 2 + 1) * NH + h) * T_SEQ + row] = s2;
        }
    }
}

// ---------------------------------------------------------------------------
// attn_b: P, partial |p| denom, partial O over the kt ≡ par (mod 2) strip.
// LDS ~33 KB single-buffered -> 4 blocks/CU. lam computed inline from
// lambda_logit + flag. Exponent-folded normalization.
// ---------------------------------------------------------------------------
__global__ __launch_bounds__(256) void attn_b(
    const u16* __restrict__ qg, const u16* __restrict__ k1g,
    const u16* __restrict__ k2g, const u16* __restrict__ vtg,
    const float* __restrict__ zp, const void* __restrict__ lamsrc,
    const int* __restrict__ flag,
    float* __restrict__ dpart, u16* __restrict__ opart) {
    __shared__ __align__(16) u16 k1s[64 * 64];
    __shared__ __align__(16) u16 k2s[64 * 64];
    __shared__ __align__(16) u16 vs[64 * 64];
    __shared__ __align__(16) u16 ps[4][16 * LS];
    ATTN_MAP();

    const int f = *flag;
    float lamlogit = f ? bf2f(((const u16*)lamsrc)[h]) : ((const float*)lamsrc)[h];
    const float lam = 1.0f / (1.0f + __expf(-lamlogit));

    const u16* qh = qg + (size_t)h * T_SEQ * HD;
    const u16* k1h = k1g + (size_t)h * T_SEQ * HD;
    const u16* k2h = k2g + (size_t)h * T_SEQ * HD;
    const u16* vh = vtg + (size_t)h * HD * T_SEQ;

    bf16x8 aq[2];
#pragma unroll
    for (int kk = 0; kk < 2; kk++)
        aq[kk] = *(const bf16x8*)(&qh[(size_t)(t0 + wm + lr) * HD + kk * 32 + quad * 8]);

    float z1l[4], z2l[4];
#pragma unroll
    for (int r = 0; r < 4; r++) {
        int row = t0 + wm + quad * 4 + r;
        float z1 = 0.f, z2 = 0.f;
#pragma unroll
        for (int p = 0; p < 4; p++) {
            z1 += zp[((size_t)(p * 2 + 0) * NH + h) * T_SEQ + row];
            z2 += zp[((size_t)(p * 2 + 1) * NH + h) * T_SEQ + row];
        }
        z1l[r] = -__log2f(z1);
        z2l[r] = __log2f(lam) - __log2f(z2);
    }

    f32x4 oac[4];
#pragma unroll
    for (int j = 0; j < 4; j++) oac[j] = (f32x4){0.f, 0.f, 0.f, 0.f};
    float dacc[4] = {0.f, 0.f, 0.f, 0.f};

    for (int kt = par; kt <= qt; kt += 2) {
        __syncthreads();
        stage_async<2>(k1h, (size_t)kt * 64, HD, 0, k1s, tid);
        stage_async<2>(k2h, (size_t)kt * 64, HD, 0, k2s, tid);
        stage_async<2>(vh, 0, T_SEQ, (size_t)kt * 64, vs, tid);
        __syncthreads();

        f32x4 sa[4], sb[4];
#pragma unroll
        for (int j = 0; j < 4; j++) { sa[j] = (f32x4){0.f,0.f,0.f,0.f}; sb[j] = (f32x4){0.f,0.f,0.f,0.f}; }
#pragma unroll
        for (int kk = 0; kk < 2; kk++) {
            const int co = ((kk * 4 + quad) ^ sw) * 8;
#pragma unroll
            for (int j = 0; j < 4; j++) {
                sa[j] = mfma16(aq[kk], frag(k1s, j * 16 + lr, co), sa[j]);
                sb[j] = mfma16(aq[kk], frag(k2s, j * 16 + lr, co), sb[j]);
            }
        }

        if (kt < qt) {
#pragma unroll
            for (int r = 0; r < 4; r++)
#pragma unroll
                for (int j = 0; j < 4; j++) {
                    float p = ex2(sa[j][r] + z1l[r]) - ex2(sb[j][r] + z2l[r]);
                    dacc[r] += fabsf(p);
                    ps[wave][(quad * 4 + r) * LS + j * 16 + lr] = f2bf_t(p);
                }
        } else {
#pragma unroll
            for (int r = 0; r < 4; r++) {
                const int grow = t0 + wm + quad * 4 + r;
#pragma unroll
                for (int j = 0; j < 4; j++) {
                    int gcol = kt * 64 + j * 16 + lr;
                    float p = 0.f;
                    if (gcol <= grow)
                        p = ex2(sa[j][r] + z1l[r]) - ex2(sb[j][r] + z2l[r]);
                    dacc[r] += fabsf(p);
                    ps[wave][(quad * 4 + r) * LS + j * 16 + lr] = f2bf_t(p);
                }
            }
        }

        // PV: wave-local LDS round trip (DS pipe in-order per wave)
#pragma unroll
        for (int kk = 0; kk < 2; kk++) {
            bf16x8 pa = *(const bf16x8*)(&ps[wave][lr * LS + kk * 32 + quad * 8]);
            const int co = ((kk * 4 + quad) ^ sw) * 8;
#pragma unroll
            for (int j = 0; j < 4; j++)
                oac[j] = mfma16(pa, frag(vs, j * 16 + lr, co), oac[j]);
        }
    }

#pragma unroll
    for (int r = 0; r < 4; r++) {
        float ds = qsum16(dacc[r]);
        if (lr == 0) {
            int row = t0 + wm + quad * 4 + r;
            dpart[((size_t)par * NH + h) * T_SEQ + row] = ds;
        }
    }
#pragma unroll
    for (int j = 0; j < 4; j++)
#pragma unroll
        for (int r = 0; r < 4; r++) {
            int row = t0 + wm + quad * 4 + r;
            opart[(size_t)par * T_SEQ * DM + (size_t)row * DM + h * HD + j * 16 + lr] =
                f2bf(oac[j][r]);
        }
}

// ---------------------------------------------------------------------------
// Output GEMM with FUSED normalization: A-rows are built during staging as
// (O0+O1) * rcp(max(d0+d1,1e-6)) from opart/dpart (sync path; per-lane cols
// k0+cg*8 stay inside one head since k0 is 64-aligned and cg*8+8 <= 64).
// B (Wo) stays async-DMA when bf16. Tile 64x64, grid (16,32) = 2 blocks/CU.
// ---------------------------------------------------------------------------
__global__ __launch_bounds__(256) void out_gemm(
    const u16* __restrict__ opart, const float* __restrict__ dpart,
    const void* __restrict__ wo, const int* __restrict__ flag,
    void* __restrict__ outp) {
    __shared__ __align__(16) u16 As[2][64 * 64];
    __shared__ __align__(16) u16 Bs[2][64 * 64];

    const int f = *flag;
    const int n0 = blockIdx.x * 64;    // 0..15
    const int m0 = blockIdx.y * 64;    // 0..31
    const u16* wb = (const u16*)wo;
    const int tid = threadIdx.x;
    const int lane = tid & 63, wave = tid >> 6;
    const int lr = lane & 15, quad = lane >> 4;
    const int wm = (wave >> 1) * 32, wn = (wave & 1) * 32;
    const int sw = lr & 7;
    const int srow = tid >> 3;         // staging row within 32-row group

    f32x4 acc[2][2];
#pragma unroll
    for (int i = 0; i < 2; i++)
#pragma unroll
        for (int j = 0; j < 2; j++) acc[i][j] = (f32x4){0.f, 0.f, 0.f, 0.f};

    if (f) stage_async<2>(wb, n0, DM, 0, Bs[0], tid);

    for (int k0 = 0; k0 < DM; k0 += 64) {
        const int cur = (k0 >> 6) & 1;
        const int hh = k0 >> 6;        // head for this k-slice (uniform)
        __syncthreads();
        // A staging: normalize inline (sync; 2 iters of 32 rows)
#pragma unroll
        for (int it = 0; it < 2; it++) {
            int r = it * 32 + srow;
            int row = m0 + r;
            int cg = (tid & 7) ^ (r & 7);
            size_t off = (size_t)row * DM + k0 + cg * 8;
            float dsum = dpart[(size_t)hh * 0 + (size_t)(0 * NH) + 0];  // placeholder opt-out
            dsum = dpart[((size_t)0 * NH + hh) * T_SEQ + row] +
                   dpart[((size_t)1 * NH + hh) * T_SEQ + row];
            float rs = 1.f / fmaxf(dsum, 1e-6f);
            uint4 a0 = *(const uint4*)(&opart[off]);
            uint4 a1 = *(const uint4*)(&opart[(size_t)T_SEQ * DM + off]);
            const u32* au = (const u32*)&a0;
            const u32* bu = (const u32*)&a1;
            uint4 outw;
            u32* ou = (u32*)&outw;
#pragma unroll
            for (int q = 0; q < 4; q++) {
                float lo = (bf2f((u16)(au[q] & 0xFFFF)) + bf2f((u16)(bu[q] & 0xFFFF))) * rs;
                float hi = (bf2f((u16)(au[q] >> 16)) + bf2f((u16)(bu[q] >> 16))) * rs;
                ou[q] = pk2(lo, hi);
            }
            *(uint4*)(&As[cur][(it * 256 + tid) * 8]) = outw;
        }
        // B staging
        if (f) {
            if (k0 + 64 < DM)
                stage_async<2>(wb, n0, DM, k0 + 64, Bs[cur ^ 1], tid);
        } else {
            stage_sync<2>(wo, n0, DM, k0, Bs[cur], tid, 0);
        }
        __syncthreads();
#pragma unroll
        for (int kk = 0; kk < 2; kk++) {
            const int co = ((kk * 4 + quad) ^ sw) * 8;
            bf16x8 af[2], bfr[2];
#pragma unroll
            for (int i = 0; i < 2; i++) af[i] = frag(As[cur], wm + i * 16 + lr, co);
#pragma unroll
            for (int j = 0; j < 2; j++) bfr[j] = frag(Bs[cur], wn + j * 16 + lr, co);
#pragma unroll
            for (int i = 0; i < 2; i++)
#pragma unroll
                for (int j = 0; j < 2; j++) acc[i][j] = mfma16(af[i], bfr[j], acc[i][j]);
        }
    }

#pragma unroll
    for (int i = 0; i < 2; i++)
#pragma unroll
        for (int j = 0; j < 2; j++)
#pragma unroll
            for (int r = 0; r < 4; r++) {
                int t = m0 + wm + i * 16 + quad * 4 + r;
                int o = n0 + wn + j * 16 + lr;
                float val = acc[i][j][r];
                if (f)
                    ((u16*)outp)[(size_t)t * DM + o] = f2bf(val);
                else
                    ((float*)outp)[(size_t)t * DM + o] = val;
            }
}

extern "C" void kernel_launch(void* const* d_in, const int* in_sizes, int n_in,
                              void* d_out, int out_size, void* d_ws, size_t ws_size,
                              hipStream_t stream) {
    char* ws = (char*)d_ws;
    int* flag = (int*)(ws + 0);
    float* zp    = (float*)(ws + ((size_t)1 << 20));   // [8][NH][T] f32 = 1 MB
    float* dpart = (float*)(ws + ((size_t)2 << 20));   // [2][NH][T] f32
    u16* qd  = (u16*)(ws + ((size_t)16 << 20));  // [H][T][64]
    u16* k1d = (u16*)(ws + ((size_t)20 << 20));
    u16* k2d = (u16*)(ws + ((size_t)24 << 20));
    u16* vtd = (u16*)(ws + ((size_t)28 << 20));  // [H][64][T]
    u16* opart = (u16*)(ws + ((size_t)36 << 20)); // [2][T][DM] bf16

    qkv_gemm<<<dim3(32, 16), 256, 0, stream>>>(d_in[0], d_in[1], d_in[2], d_in[3],
                                               d_in[4], flag, qd, k1d, k2d, vtd);
    attn_a<<<dim3(2048), 256, 0, stream>>>(qd, k1d, k2d, zp);
    attn_b<<<dim3(1024), 256, 0, stream>>>(qd, k1d, k2d, vtd, zp, d_in[6], flag,
                                           dpart, opart);
    out_gemm<<<dim3(16, 32), 256, 0, stream>>>(opart, dpart, d_in[5], flag, d_out);
}

// Round 11
// 201.459 us; speedup vs baseline: 1.0360x; 1.0360x over previous
//
#include <hip/hip_runtime.h>

#define T_SEQ 2048
#define DM 1024
#define NH 16
#define HD 64
// SCALE * log2(e) : softmax computed in exp2 domain (folded into Q in qkv_gemm)
#define SC2 0.1803368801111731f
#define LS 72   // ps LDS row stride (u16); 144 B rows: 16B-aligned, 2-way banks (free)

typedef unsigned short u16;
typedef unsigned int u32;
typedef __attribute__((ext_vector_type(8))) short bf16x8;
typedef __attribute__((ext_vector_type(4))) float f32x4;

static __device__ __forceinline__ f32x4 mfma16(bf16x8 a, bf16x8 b, f32x4 c) {
    return __builtin_amdgcn_mfma_f32_16x16x32_bf16(a, b, c, 0, 0, 0);
}
static __device__ __forceinline__ float bf2f(u16 u) {
    union { u32 i; float f; } v; v.i = ((u32)u) << 16; return v.f;
}
static __device__ __forceinline__ u16 f2bf(float f) {
    union { float f; u32 i; } v; v.f = f;
    u32 x = v.i;
    x += 0x7FFFu + ((x >> 16) & 1u);   // RNE
    return (u16)(x >> 16);
}
static __device__ __forceinline__ u16 f2bf_t(float f) {   // truncating (1 op)
    union { float f; u32 i; } v; v.f = f;
    return (u16)(v.i >> 16);
}
static __device__ __forceinline__ u32 pk2(float lo, float hi) {
    return (u32)f2bf(lo) | ((u32)f2bf(hi) << 16);
}
// load 8 contiguous elements as packed bf16; converts from f32 if f==0.
static __device__ __forceinline__ uint4 ld8(const void* src, size_t idx, int f) {
    if (f) return *(const uint4*)((const u16*)src + idx);
    const float* s = (const float*)src + idx;
    uint4 a = *(const uint4*)s;
    uint4 b = *(const uint4*)(s + 4);
    const float* af = (const float*)&a;
    const float* bf = (const float*)&b;
    uint4 r;
    r.x = pk2(af[0], af[1]); r.y = pk2(af[2], af[3]);
    r.z = pk2(bf[0], bf[1]); r.w = pk2(bf[2], bf[3]);
    return r;
}
static __device__ __forceinline__ float qsum16(float v) {
#pragma unroll
    for (int o = 1; o < 16; o <<= 1) v += __shfl_xor(v, o, 64);
    return v;
}
static __device__ __forceinline__ float ex2(float x) {
    return __builtin_amdgcn_exp2f(x);
}

// Async global->LDS DMA, 16 B per lane.
static __device__ __forceinline__ void gl16(const u16* g, u16* l) {
    __builtin_amdgcn_global_load_lds(
        (const __attribute__((address_space(1))) void*)g,
        (__attribute__((address_space(3))) void*)l,
        16, 0, 0);
}

// ---------------------------------------------------------------------------
// Staging into unpadded LDS (row stride 64 u16 = 128 B) with XOR chunk
// swizzle: LDS slot (r, c) holds global chunk c^(r&7). Global side fully
// coalesced; b128 fragment reads land 2-way (free). r7 lesson: direct
// global fragment loads (no LDS) are 16x transaction-amplified -- keep LDS.
// ---------------------------------------------------------------------------
template <int NISS>
static __device__ __forceinline__ void stage_async(const u16* src, size_t row0,
                                                   size_t lds_, size_t col0,
                                                   u16* dst, int tid) {
#pragma unroll
    for (int it = 0; it < NISS; it++) {
        int r = it * 32 + (tid >> 3);
        int cg = (tid & 7) ^ (r & 7);
        gl16(&src[(row0 + r) * lds_ + col0 + cg * 8], &dst[(it * 256 + tid) * 8]);
    }
}
template <int NISS>
static __device__ __forceinline__ void stage_sync(const void* src, size_t row0,
                                                  size_t lds_, size_t col0,
                                                  u16* dst, int tid, int f) {
#pragma unroll
    for (int it = 0; it < NISS; it++) {
        int r = it * 32 + (tid >> 3);
        int cg = (tid & 7) ^ (r & 7);
        *(uint4*)(&dst[(it * 256 + tid) * 8]) =
            ld8(src, (row0 + r) * lds_ + col0 + cg * 8, f);
    }
}
static __device__ __forceinline__ bf16x8 frag(const u16* buf, int R, int co) {
    return *(const bf16x8*)(&buf[R * 64 + co]);
}

// dtype self-detect helper: count plausible bf16 exponents in first 1024
// even-index u16s of x. bf16 N(0,1) -> ~100% hit; f32 mantissa halves ~12%.
static __device__ __forceinline__ int detect_flag(const u16* x, int tid,
                                                  int* tot /*LDS*/) {
    if (tid == 0) *tot = 0;
    __syncthreads();
    int c = 0;
#pragma unroll
    for (int i = 0; i < 4; i++) {
        u16 v = x[2 * (tid * 4 + i)];
        int e = (v >> 7) & 0xFF;
        c += (e >= 110 && e <= 140) ? 1 : 0;
    }
    atomicAdd(tot, c);
    __syncthreads();
    return (*tot >= 512) ? 1 : 0;
}

// ---------------------------------------------------------------------------
// QKV(+V-transpose) projection GEMM. Tile 128x128xK64, async DMA dbuf
// (64 KB LDS -> 2 blocks/CU; grid 512). Self-detects dtype flag (publishes
// to ws for downstream kernels). Q output pre-scaled by SC2.
// Parked at the m97-structure plateau (~240 TF at this shape, m102 curve).
// ---------------------------------------------------------------------------
__global__ __launch_bounds__(256) void qkv_gemm(
    const void* __restrict__ xs, const void* __restrict__ wq,
    const void* __restrict__ wk1, const void* __restrict__ wk2,
    const void* __restrict__ wv, int* __restrict__ flag,
    u16* __restrict__ qd, u16* __restrict__ k1d, u16* __restrict__ k2d,
    u16* __restrict__ vtd) {
    __shared__ __align__(16) u16 As[2][128 * 64];
    __shared__ __align__(16) u16 Bs[2][128 * 64];
    __shared__ int flg_tot;

    const int tid = threadIdx.x;
    const int f = detect_flag((const u16*)xs, tid, &flg_tot);
    if (blockIdx.x == 0 && blockIdx.y == 0 && tid == 0) *flag = f;

    const int w = blockIdx.x >> 3;
    const int n0 = (blockIdx.x & 7) * 128;
    const int m0 = blockIdx.y * 128;
    const void* Bpv = (w == 0) ? wq : (w == 1) ? wk1 : (w == 2) ? wk2 : wv;
    const u16* xb = (const u16*)xs;
    const u16* Bb = (const u16*)Bpv;

    const int lane = tid & 63, wave = tid >> 6;
    const int lr = lane & 15, quad = lane >> 4;
    const int wm = (wave >> 1) * 64, wn = (wave & 1) * 64;
    const int sw = lr & 7;

    f32x4 acc[4][4];
#pragma unroll
    for (int i = 0; i < 4; i++)
#pragma unroll
        for (int j = 0; j < 4; j++) acc[i][j] = (f32x4){0.f, 0.f, 0.f, 0.f};

    if (f) {
        stage_async<4>(xb, m0, DM, 0, As[0], tid);
        stage_async<4>(Bb, n0, DM, 0, Bs[0], tid);
    }
    for (int k0 = 0; k0 < DM; k0 += 64) {
        const int cur = (k0 >> 6) & 1;
        __syncthreads();
        if (f) {
            if (k0 + 64 < DM) {
                stage_async<4>(xb, m0, DM, k0 + 64, As[cur ^ 1], tid);
                stage_async<4>(Bb, n0, DM, k0 + 64, Bs[cur ^ 1], tid);
            }
        } else {
            stage_sync<4>(xs, m0, DM, k0, As[cur], tid, 0);
            stage_sync<4>(Bpv, n0, DM, k0, Bs[cur], tid, 0);
            __syncthreads();
        }
#pragma unroll
        for (int kk = 0; kk < 2; kk++) {
            const int co = ((kk * 4 + quad) ^ sw) * 8;
            bf16x8 af[4], bfr[4];
#pragma unroll
            for (int i = 0; i < 4; i++) af[i] = frag(As[cur], wm + i * 16 + lr, co);
#pragma unroll
            for (int j = 0; j < 4; j++) bfr[j] = frag(Bs[cur], wn + j * 16 + lr, co);
#pragma unroll
            for (int i = 0; i < 4; i++)
#pragma unroll
                for (int j = 0; j < 4; j++) acc[i][j] = mfma16(af[i], bfr[j], acc[i][j]);
        }
    }

#pragma unroll
    for (int i = 0; i < 4; i++)
#pragma unroll
        for (int j = 0; j < 4; j++)
#pragma unroll
            for (int r = 0; r < 4; r++) {
                int t = m0 + wm + i * 16 + quad * 4 + r;
                int o = n0 + wn + j * 16 + lr;
                float val = acc[i][j][r];
                if (w == 0) val *= SC2;               // fold softmax scale into Q
                u16 vbits = f2bf(val);
                int hh = o >> 6, d0 = o & 63;
                if (w == 3)
                    vtd[((size_t)hh * HD + d0) * T_SEQ + t] = vbits;   // v transposed
                else
                    ((w == 0) ? qd : (w == 1) ? k1d : k2d)[((size_t)hh * T_SEQ + t) * HD + d0] = vbits;
            }
}

// ---------------------------------------------------------------------------
// Mapping for attn_a/attn_b: b -> (par, h, qt). par = b>>9 (attn_a grid 2048
// -> par 0..3; attn_b grid 1024 -> par 0..1). Within a 512-group, CU-paired
// qt balance: {qt, 31-qt}. Block processes strip kt ≡ par (mod npar).
// ---------------------------------------------------------------------------
#define ATTN_MAP()                                            \
    const int b = blockIdx.x;                                 \
    const int par = b >> 9;                                   \
    const int rem = b & 511;                                  \
    const int h = rem & 15;                                   \
    const int bi = rem >> 4;                                  \
    const int qt = (bi < 16) ? bi : 47 - bi;                  \
    const int t0 = qt * 64;                                   \
    const int tid = threadIdx.x;                              \
    const int lane = tid & 63, wave = tid >> 6;               \
    const int lr = lane & 15, quad = lane >> 4;               \
    const int wm = wave * 16;                                 \
    const int sw = lr & 7;

// ---------------------------------------------------------------------------
// attn_a: partial Z1/Z2 over the kt ≡ par (mod 4) strip. Grid 2048 ->
// 8 blocks/CU (16 KB LDS). zp: [par*2+which][NH][T] f32.
// ---------------------------------------------------------------------------
__global__ __launch_bounds__(256) void attn_a(
    const u16* __restrict__ qg, const u16* __restrict__ k1g,
    const u16* __restrict__ k2g, float* __restrict__ zp) {
    __shared__ __align__(16) u16 k1s[64 * 64];
    __shared__ __align__(16) u16 k2s[64 * 64];
    ATTN_MAP();

    const u16* qh = qg + (size_t)h * T_SEQ * HD;
    const u16* k1h = k1g + (size_t)h * T_SEQ * HD;
    const u16* k2h = k2g + (size_t)h * T_SEQ * HD;

    bf16x8 aq[2];
#pragma unroll
    for (int kk = 0; kk < 2; kk++)
        aq[kk] = *(const bf16x8*)(&qh[(size_t)(t0 + wm + lr) * HD + kk * 32 + quad * 8]);

    float z1a[4] = {0.f, 0.f, 0.f, 0.f}, z2a[4] = {0.f, 0.f, 0.f, 0.f};

    for (int kt = par; kt <= qt; kt += 4) {
        __syncthreads();   // protect LDS from previous iteration's readers
        stage_async<2>(k1h, (size_t)kt * 64, HD, 0, k1s, tid);
        stage_async<2>(k2h, (size_t)kt * 64, HD, 0, k2s, tid);
        __syncthreads();   // drains vmcnt -> data visible

        f32x4 sa[4], sb[4];
#pragma unroll
        for (int j = 0; j < 4; j++) { sa[j] = (f32x4){0.f,0.f,0.f,0.f}; sb[j] = (f32x4){0.f,0.f,0.f,0.f}; }
#pragma unroll
        for (int kk = 0; kk < 2; kk++) {
            const int co = ((kk * 4 + quad) ^ sw) * 8;
#pragma unroll
            for (int j = 0; j < 4; j++) {
                sa[j] = mfma16(aq[kk], frag(k1s, j * 16 + lr, co), sa[j]);
                sb[j] = mfma16(aq[kk], frag(k2s, j * 16 + lr, co), sb[j]);
            }
        }

        if (kt < qt) {
#pragma unroll
            for (int r = 0; r < 4; r++)
#pragma unroll
                for (int j = 0; j < 4; j++) {
                    z1a[r] += ex2(sa[j][r]);
                    z2a[r] += ex2(sb[j][r]);
                }
        } else {
#pragma unroll
            for (int r = 0; r < 4; r++) {
                const int grow = t0 + wm + quad * 4 + r;
#pragma unroll
                for (int j = 0; j < 4; j++) {
                    int gcol = kt * 64 + j * 16 + lr;
                    if (gcol <= grow) {
                        z1a[r] += ex2(sa[j][r]);
                        z2a[r] += ex2(sb[j][r]);
                    }
                }
            }
        }
    }

#pragma unroll
    for (int r = 0; r < 4; r++) {
        float s1 = qsum16(z1a[r]);
        float s2 = qsum16(z2a[r]);
        if (lr == 0) {
            int row = t0 + wm + quad * 4 + r;
            zp[((size_t)(par * 2 + 0) * NH + h) * T_SEQ + row] = s1;
            zp[((size_t)(par * 2 + 1) * NH + h) * T_SEQ + row] = s2;
        }
    }
}

// ---------------------------------------------------------------------------
// attn_b: P, partial |p| denom, partial O over the kt ≡ par (mod 2) strip.
// LDS ~33 KB single-buffered -> 4 blocks/CU. lam computed inline from
// lambda_logit + flag. Exponent-folded normalization.
// ---------------------------------------------------------------------------
__global__ __launch_bounds__(256) void attn_b(
    const u16* __restrict__ qg, const u16* __restrict__ k1g,
    const u16* __restrict__ k2g, const u16* __restrict__ vtg,
    const float* __restrict__ zp, const void* __restrict__ lamsrc,
    const int* __restrict__ flag,
    float* __restrict__ dpart, u16* __restrict__ opart) {
    __shared__ __align__(16) u16 k1s[64 * 64];
    __shared__ __align__(16) u16 k2s[64 * 64];
    __shared__ __align__(16) u16 vs[64 * 64];
    __shared__ __align__(16) u16 ps[4][16 * LS];
    ATTN_MAP();

    const int f = *flag;
    float lamlogit = f ? bf2f(((const u16*)lamsrc)[h]) : ((const float*)lamsrc)[h];
    const float lam = 1.0f / (1.0f + __expf(-lamlogit));

    const u16* qh = qg + (size_t)h * T_SEQ * HD;
    const u16* k1h = k1g + (size_t)h * T_SEQ * HD;
    const u16* k2h = k2g + (size_t)h * T_SEQ * HD;
    const u16* vh = vtg + (size_t)h * HD * T_SEQ;

    bf16x8 aq[2];
#pragma unroll
    for (int kk = 0; kk < 2; kk++)
        aq[kk] = *(const bf16x8*)(&qh[(size_t)(t0 + wm + lr) * HD + kk * 32 + quad * 8]);

    float z1l[4], z2l[4];
#pragma unroll
    for (int r = 0; r < 4; r++) {
        int row = t0 + wm + quad * 4 + r;
        float z1 = 0.f, z2 = 0.f;
#pragma unroll
        for (int p = 0; p < 4; p++) {
            z1 += zp[((size_t)(p * 2 + 0) * NH + h) * T_SEQ + row];
            z2 += zp[((size_t)(p * 2 + 1) * NH + h) * T_SEQ + row];
        }
        z1l[r] = -__log2f(z1);
        z2l[r] = __log2f(lam) - __log2f(z2);
    }

    f32x4 oac[4];
#pragma unroll
    for (int j = 0; j < 4; j++) oac[j] = (f32x4){0.f, 0.f, 0.f, 0.f};
    float dacc[4] = {0.f, 0.f, 0.f, 0.f};

    for (int kt = par; kt <= qt; kt += 2) {
        __syncthreads();
        stage_async<2>(k1h, (size_t)kt * 64, HD, 0, k1s, tid);
        stage_async<2>(k2h, (size_t)kt * 64, HD, 0, k2s, tid);
        stage_async<2>(vh, 0, T_SEQ, (size_t)kt * 64, vs, tid);
        __syncthreads();

        f32x4 sa[4], sb[4];
#pragma unroll
        for (int j = 0; j < 4; j++) { sa[j] = (f32x4){0.f,0.f,0.f,0.f}; sb[j] = (f32x4){0.f,0.f,0.f,0.f}; }
#pragma unroll
        for (int kk = 0; kk < 2; kk++) {
            const int co = ((kk * 4 + quad) ^ sw) * 8;
#pragma unroll
            for (int j = 0; j < 4; j++) {
                sa[j] = mfma16(aq[kk], frag(k1s, j * 16 + lr, co), sa[j]);
                sb[j] = mfma16(aq[kk], frag(k2s, j * 16 + lr, co), sb[j]);
            }
        }

        if (kt < qt) {
#pragma unroll
            for (int r = 0; r < 4; r++)
#pragma unroll
                for (int j = 0; j < 4; j++) {
                    float p = ex2(sa[j][r] + z1l[r]) - ex2(sb[j][r] + z2l[r]);
                    dacc[r] += fabsf(p);
                    ps[wave][(quad * 4 + r) * LS + j * 16 + lr] = f2bf_t(p);
                }
        } else {
#pragma unroll
            for (int r = 0; r < 4; r++) {
                const int grow = t0 + wm + quad * 4 + r;
#pragma unroll
                for (int j = 0; j < 4; j++) {
                    int gcol = kt * 64 + j * 16 + lr;
                    float p = 0.f;
                    if (gcol <= grow)
                        p = ex2(sa[j][r] + z1l[r]) - ex2(sb[j][r] + z2l[r]);
                    dacc[r] += fabsf(p);
                    ps[wave][(quad * 4 + r) * LS + j * 16 + lr] = f2bf_t(p);
                }
            }
        }

        // PV: wave-local LDS round trip (DS pipe in-order per wave)
#pragma unroll
        for (int kk = 0; kk < 2; kk++) {
            bf16x8 pa = *(const bf16x8*)(&ps[wave][lr * LS + kk * 32 + quad * 8]);
            const int co = ((kk * 4 + quad) ^ sw) * 8;
#pragma unroll
            for (int j = 0; j < 4; j++)
                oac[j] = mfma16(pa, frag(vs, j * 16 + lr, co), oac[j]);
        }
    }

#pragma unroll
    for (int r = 0; r < 4; r++) {
        float ds = qsum16(dacc[r]);
        if (lr == 0) {
            int row = t0 + wm + quad * 4 + r;
            dpart[((size_t)par * NH + h) * T_SEQ + row] = ds;
        }
    }
#pragma unroll
    for (int j = 0; j < 4; j++)
#pragma unroll
        for (int r = 0; r < 4; r++) {
            int row = t0 + wm + quad * 4 + r;
            opart[(size_t)par * T_SEQ * DM + (size_t)row * DM + h * HD + j * 16 + lr] =
                f2bf(oac[j][r]);
        }
}

// ---------------------------------------------------------------------------
// normalize: ao[t][d] = (O0+O1) / max(d0+d1, 1e-6). Standalone memory-bound
// kernel -- r10 showed fusing this into out_gemm's staging path regresses
// (sync latency inserted into a 2-blocks/CU GEMM loop with no TLP cover).
// ---------------------------------------------------------------------------
__global__ __launch_bounds__(256) void normalize_o(
    const u16* __restrict__ opart, const float* __restrict__ dpart,
    u16* __restrict__ ao) {
    int g = blockIdx.x * 256 + threadIdx.x;
    int t = g >> 7;
    int cc = g & 127;
    int d0 = cc * 8;
    int h = d0 >> 6;
    float dsum = dpart[(size_t)h * T_SEQ + t] + dpart[(size_t)(NH + h) * T_SEQ + t];
    float rs = 1.f / fmaxf(dsum, 1e-6f);
    uint4 a = *(const uint4*)(&opart[(size_t)t * DM + d0]);
    uint4 bqq = *(const uint4*)(&opart[(size_t)T_SEQ * DM + (size_t)t * DM + d0]);
    const u32* au = (const u32*)&a;
    const u32* bu = (const u32*)&bqq;
    uint4 out;
    u32* ou = (u32*)&out;
#pragma unroll
    for (int i = 0; i < 4; i++) {
        float lo = (bf2f((u16)(au[i] & 0xFFFF)) + bf2f((u16)(bu[i] & 0xFFFF))) * rs;
        float hi = (bf2f((u16)(au[i] >> 16)) + bf2f((u16)(bu[i] >> 16))) * rs;
        ou[i] = pk2(lo, hi);
    }
    *(uint4*)(&ao[(size_t)t * DM + d0]) = out;
}

// ---------------------------------------------------------------------------
// Output GEMM: out = ao @ Wo^T. Tile 64x64 -> grid (16,32) = 512 blocks =
// 2 blocks/CU. 4 waves 2x2, wave = 32x32 (acc[2][2]). Async dbuf staging.
// ---------------------------------------------------------------------------
__global__ __launch_bounds__(256) void out_gemm(
    const u16* __restrict__ ab, const void* __restrict__ wo,
    const int* __restrict__ flag, void* __restrict__ outp) {
    __shared__ __align__(16) u16 As[2][64 * 64];
    __shared__ __align__(16) u16 Bs[2][64 * 64];

    const int f = *flag;
    const int n0 = blockIdx.x * 64;    // 0..15
    const int m0 = blockIdx.y * 64;    // 0..31
    const u16* wb = (const u16*)wo;
    const int tid = threadIdx.x;
    const int lane = tid & 63, wave = tid >> 6;
    const int lr = lane & 15, quad = lane >> 4;
    const int wm = (wave >> 1) * 32, wn = (wave & 1) * 32;
    const int sw = lr & 7;

    f32x4 acc[2][2];
#pragma unroll
    for (int i = 0; i < 2; i++)
#pragma unroll
        for (int j = 0; j < 2; j++) acc[i][j] = (f32x4){0.f, 0.f, 0.f, 0.f};

    if (f) {
        stage_async<2>(ab, m0, DM, 0, As[0], tid);
        stage_async<2>(wb, n0, DM, 0, Bs[0], tid);
    }
    for (int k0 = 0; k0 < DM; k0 += 64) {
        const int cur = (k0 >> 6) & 1;
        __syncthreads();
        if (f) {
            if (k0 + 64 < DM) {
                stage_async<2>(ab, m0, DM, k0 + 64, As[cur ^ 1], tid);
                stage_async<2>(wb, n0, DM, k0 + 64, Bs[cur ^ 1], tid);
            }
        } else {
            stage_sync<2>(ab, m0, DM, k0, As[cur], tid, 1);
            stage_sync<2>(wo, n0, DM, k0, Bs[cur], tid, 0);
            __syncthreads();
        }
#pragma unroll
        for (int kk = 0; kk < 2; kk++) {
            const int co = ((kk * 4 + quad) ^ sw) * 8;
            bf16x8 af[2], bfr[2];
#pragma unroll
            for (int i = 0; i < 2; i++) af[i] = frag(As[cur], wm + i * 16 + lr, co);
#pragma unroll
            for (int j = 0; j < 2; j++) bfr[j] = frag(Bs[cur], wn + j * 16 + lr, co);
#pragma unroll
            for (int i = 0; i < 2; i++)
#pragma unroll
                for (int j = 0; j < 2; j++) acc[i][j] = mfma16(af[i], bfr[j], acc[i][j]);
        }
    }

#pragma unroll
    for (int i = 0; i < 2; i++)
#pragma unroll
        for (int j = 0; j < 2; j++)
#pragma unroll
            for (int r = 0; r < 4; r++) {
                int t = m0 + wm + i * 16 + quad * 4 + r;
                int o = n0 + wn + j * 16 + lr;
                float val = acc[i][j][r];
                if (f)
                    ((u16*)outp)[(size_t)t * DM + o] = f2bf(val);
                else
                    ((float*)outp)[(size_t)t * DM + o] = val;
            }
}

extern "C" void kernel_launch(void* const* d_in, const int* in_sizes, int n_in,
                              void* d_out, int out_size, void* d_ws, size_t ws_size,
                              hipStream_t stream) {
    char* ws = (char*)d_ws;
    int* flag = (int*)(ws + 0);
    float* zp    = (float*)(ws + ((size_t)1 << 20));   // [8][NH][T] f32 = 1 MB
    float* dpart = (float*)(ws + ((size_t)2 << 20));   // [2][NH][T] f32
    u16* qd  = (u16*)(ws + ((size_t)16 << 20));  // [H][T][64]
    u16* k1d = (u16*)(ws + ((size_t)20 << 20));
    u16* k2d = (u16*)(ws + ((size_t)24 << 20));
    u16* vtd = (u16*)(ws + ((size_t)28 << 20));  // [H][64][T]
    u16* ao  = (u16*)(ws + ((size_t)32 << 20));  // [T][DM] bf16
    u16* opart = (u16*)(ws + ((size_t)36 << 20)); // [2][T][DM] bf16

    qkv_gemm<<<dim3(32, 16), 256, 0, stream>>>(d_in[0], d_in[1], d_in[2], d_in[3],
                                               d_in[4], flag, qd, k1d, k2d, vtd);
    attn_a<<<dim3(2048), 256, 0, stream>>>(qd, k1d, k2d, zp);
    attn_b<<<dim3(1024), 256, 0, stream>>>(qd, k1d, k2d, vtd, zp, d_in[6], flag,
                                           dpart, opart);
    normalize_o<<<dim3(1024), 256, 0, stream>>>(opart, dpart, ao);
    out_gemm<<<dim3(16, 32), 256, 0, stream>>>(ao, d_in[5], flag, d_out);
}